// Round 8
// baseline (458.702 us; speedup 1.0000x reference)
//
#include <hip/hip_runtime.h>
#include <hip/hip_bf16.h>

// Problem constants (T,K,E,H,I) = (1024, 2, 8, 2048, 1024)
#define T_TOK 1024
#define KSEL  2
#define NEXP  8
#define HDIM  2048
#define IDIM  1024
#define TK    2048            // (token, slot) pairs

typedef float  f32x4  __attribute__((ext_vector_type(4)));
typedef __bf16 bf16x8 __attribute__((ext_vector_type(8)));
typedef __bf16 bf16x2 __attribute__((ext_vector_type(2)));

__device__ __forceinline__ unsigned short f2bf(float f) {
    union { float f; unsigned u; } v; v.f = f;
    unsigned r = (v.u >> 16) & 1u;               // round-to-nearest-even
    return (unsigned short)((v.u + 0x7fffu + r) >> 16);
}

__device__ __forceinline__ unsigned pk2bf(float lo, float hi) {
#if __has_builtin(__builtin_amdgcn_cvt_pk_bf16_f32)
    bf16x2 v = __builtin_amdgcn_cvt_pk_bf16_f32(lo, hi);
    union { bf16x2 v; unsigned u; } c; c.v = v;
    return c.u;
#else
    return (unsigned)f2bf(lo) | ((unsigned)f2bf(hi) << 16);
#endif
}

// two float4 (8 consecutive fp32 along k) -> one bf16x8 MFMA operand
__device__ __forceinline__ bf16x8 cvt8(float4 a, float4 b) {
    union { unsigned u[4]; bf16x8 v; } c;
    c.u[0] = pk2bf(a.x, a.y); c.u[1] = pk2bf(a.z, a.w);
    c.u[2] = pk2bf(b.x, b.y); c.u[3] = pk2bf(b.z, b.w);
    return c.v;
}

// ---------------------------------------------------------------------------
// Kernel 1: prep = hidden fp32->bf16 (all blocks) + expert counting-sort
// (block 0 only). Grid 1024 x 256 covers T*H/8 = 262144 chunks exactly.
// ---------------------------------------------------------------------------
__global__ __launch_bounds__(256) void prep(
    const float* __restrict__ hidden, const int* __restrict__ sel,
    unsigned short* __restrict__ hid_bf, int* __restrict__ meta,
    int* __restrict__ pairs)
{
    const int t = blockIdx.x * 256 + threadIdx.x;
    {
        const float* s = hidden + (size_t)t * 8;
        float4 v0 = *(const float4*)s;
        float4 v1 = *(const float4*)(s + 4);
        uint4 o;
        o.x = pk2bf(v0.x, v0.y); o.y = pk2bf(v0.z, v0.w);
        o.z = pk2bf(v1.x, v1.y); o.w = pk2bf(v1.z, v1.w);
        *(uint4*)(hid_bf + (size_t)t * 8) = o;
    }
    if (blockIdx.x == 0) {
        __shared__ int lcnt[NEXP], lstart[NEXP], lfill[NEXP];
        const int tid = threadIdx.x;
        if (tid < NEXP) { lcnt[tid] = 0; lfill[tid] = 0; }
        __syncthreads();
        for (int i = tid; i < TK; i += 256) atomicAdd(&lcnt[sel[i]], 1);
        __syncthreads();
        if (tid == 0) {
            int s2 = 0;
            for (int e2 = 0; e2 < NEXP; ++e2) { lstart[e2] = s2; s2 += lcnt[e2]; }
        }
        __syncthreads();
        for (int i = tid; i < TK; i += 256) {
            int e2 = sel[i];
            pairs[lstart[e2] + atomicAdd(&lfill[e2], 1)] = i;   // i == t*K+k
        }
        if (tid < NEXP) { meta[tid] = lcnt[tid]; meta[NEXP + tid] = lstart[tid]; }
    }
}

// ---------------------------------------------------------------------------
// Kernel 2: gate_up GEMM + SiLU*up -> bf16 inter. BARRIER-FREE, LDS-FREE.
// Each wave owns M=64 packed rows x N=16 inter cols (16 gate + 16 up weight
// rows). B fragments loaded straight from gup fp32 (lane l16 = weight row,
// quad = k-chunk; 16 rows x 128B fully-used lines), cvt_pk'd to bf16 in-reg.
// A fragments direct from hid_bf (XCD-local L2; e=bx&7 pins expert->XCD).
// No __syncthreads => compiler emits fine-grained vmcnt(N); 2-slab B
// prefetch + 1-slab A prefetch actually survive. K-slab 64, NK=32.
// Grid: 8 experts x 96 blocks x 4 waves; wave decode widx=(bx>>3)*4+w,
// nt=widx/6 in [0,64), mi=widx%6 (m0=64*mi covers cnt<=384). A block's 4
// waves share one nt => B line reuse is temporally tight in L2.
// ---------------------------------------------------------------------------
__global__ __launch_bounds__(256, 2) void gemm1_gateup(
    const unsigned short* __restrict__ hid_bf, const float* __restrict__ gup,
    const int* __restrict__ meta, const int* __restrict__ pairs,
    unsigned short* __restrict__ inter)
{
    const int bx = blockIdx.x;
    const int e = bx & 7;
    const int tid = threadIdx.x;
    const int lane = tid & 63, w = tid >> 6;
    const int quad = lane >> 4, l16 = lane & 15;
    const int widx = (bx >> 3) * 4 + w;
    const int nt = widx / 6, mi = widx - nt * 6;
    const int cnt = meta[e];
    const int m0 = mi * 64;
    if (m0 >= cnt) return;                 // wave-uniform; no barriers anywhere
    const int seg = meta[8 + e];
    const int n0 = nt * 16;

    // A fragment pointers: 4 m-frags of 16 rows; lane row = l16.
    const unsigned short* ap[4];
    #pragma unroll
    for (int i = 0; i < 4; ++i) {
        int mr  = m0 + i * 16 + l16;
        int idx = seg + min(mr, cnt - 1);          // clamp; dup rows masked at store
        ap[i] = hid_bf + (size_t)(pairs[idx] >> 1) * HDIM + quad * 8;
    }
    // B row pointers (fp32): gate row n0+l16, up row IDIM+n0+l16.
    const float* __restrict__ bpg =
        gup + (size_t)e * (2 * IDIM * HDIM) + (size_t)(n0 + l16) * HDIM + quad * 8;
    const float* __restrict__ bpu =
        gup + (size_t)e * (2 * IDIM * HDIM) + (size_t)(IDIM + n0 + l16) * HDIM + quad * 8;

    f32x4 accg[4], accu[4];
    const f32x4 zero = {0.f, 0.f, 0.f, 0.f};
    #pragma unroll
    for (int i = 0; i < 4; ++i) { accg[i] = zero; accu[i] = zero; }

    float4 Rg0[2][2], Ru0[2][2], Rg1[2][2], Ru1[2][2];   // raw B, 2-slab deep
    bf16x8 afA[4][2], afB[4][2];                         // A frags, 1-slab deep

    auto loadB = [&](float4 (&Rg)[2][2], float4 (&Ru)[2][2], int s) {
        #pragma unroll
        for (int kk = 0; kk < 2; ++kk) {
            const int o = s * 64 + kk * 32;
            Rg[kk][0] = *(const float4*)(bpg + o);
            Rg[kk][1] = *(const float4*)(bpg + o + 4);
            Ru[kk][0] = *(const float4*)(bpu + o);
            Ru[kk][1] = *(const float4*)(bpu + o + 4);
        }
    };
    auto loadA = [&](bf16x8 (&af)[4][2], int s) {
        #pragma unroll
        for (int i = 0; i < 4; ++i)
            #pragma unroll
            for (int kk = 0; kk < 2; ++kk)
                af[i][kk] = *(const bf16x8*)(ap[i] + s * 64 + kk * 32);
    };
    auto compute = [&](const bf16x8 (&af)[4][2],
                       const float4 (&Rg)[2][2], const float4 (&Ru)[2][2]) {
        #pragma unroll
        for (int kk = 0; kk < 2; ++kk) {
            bf16x8 bg = cvt8(Rg[kk][0], Rg[kk][1]);
            bf16x8 bu = cvt8(Ru[kk][0], Ru[kk][1]);
            #pragma unroll
            for (int i = 0; i < 4; ++i) {
                accg[i] = __builtin_amdgcn_mfma_f32_16x16x32_bf16(af[i][kk], bg, accg[i], 0, 0, 0);
                accu[i] = __builtin_amdgcn_mfma_f32_16x16x32_bf16(af[i][kk], bu, accu[i], 0, 0, 0);
            }
        }
    };

    const int NK = HDIM / 64;   // 32
    loadB(Rg0, Ru0, 0);
    loadA(afA, 0);
    loadB(Rg1, Ru1, 1);
    for (int s = 0; s < NK; s += 2) {
        loadA(afB, s + 1);                       // A for s+1 (s+1 < NK always)
        compute(afA, Rg0, Ru0);                  // slab s
        if (s + 2 < NK) { loadB(Rg0, Ru0, s + 2); loadA(afA, s + 2); }
        compute(afB, Rg1, Ru1);                  // slab s+1
        if (s + 3 < NK) loadB(Rg1, Ru1, s + 3);
    }

    // Epilogue: silu(gate)*up -> inter (packed rows, bf16). col = n0 + l16.
    #pragma unroll
    for (int i = 0; i < 4; ++i) {
        #pragma unroll
        for (int r = 0; r < 4; ++r) {
            int mrow = m0 + i * 16 + quad * 4 + r;
            if (mrow < cnt) {
                float g = accg[i][r], u = accu[i][r];
                float sv = g * (1.f / (1.f + __expf(-g)));
                inter[(size_t)(seg + mrow) * IDIM + n0 + l16] = f2bf(sv * u);
            }
        }
    }
}

// ---------------------------------------------------------------------------
// Kernel 3: down-proj GEMM, same barrier-free skeleton. Wave = M64 x N32
// (2 col-frags), B = down fp32 direct + in-reg cvt, A = inter bf16 from L2.
// K-slab 64, NK=16. Output fp32 scattered to out[pairs[p]].
// ---------------------------------------------------------------------------
__global__ __launch_bounds__(256, 2) void gemm2_down(
    const unsigned short* __restrict__ inter, const float* __restrict__ down,
    const int* __restrict__ meta, const int* __restrict__ pairs,
    float* __restrict__ out)
{
    const int bx = blockIdx.x;
    const int e = bx & 7;
    const int tid = threadIdx.x;
    const int lane = tid & 63, w = tid >> 6;
    const int quad = lane >> 4, l16 = lane & 15;
    const int widx = (bx >> 3) * 4 + w;
    const int nt = widx / 6, mi = widx - nt * 6;   // nt in [0,64): 64 x 32 = HDIM
    const int cnt = meta[e];
    const int m0 = mi * 64;
    if (m0 >= cnt) return;
    const int seg = meta[8 + e];
    const int n0 = nt * 32;

    const unsigned short* ap[4];
    #pragma unroll
    for (int i = 0; i < 4; ++i) {
        int mr  = m0 + i * 16 + l16;
        int idx = seg + min(mr, cnt - 1);
        ap[i] = inter + (size_t)idx * IDIM + quad * 8;
    }
    // B rows: n0 + j*16 + l16, j<2.
    const float* __restrict__ bp0 =
        down + (size_t)e * (HDIM * IDIM) + (size_t)(n0 + l16) * IDIM + quad * 8;
    const float* __restrict__ bp1 =
        down + (size_t)e * (HDIM * IDIM) + (size_t)(n0 + 16 + l16) * IDIM + quad * 8;

    f32x4 acc[4][2];
    const f32x4 zero = {0.f, 0.f, 0.f, 0.f};
    #pragma unroll
    for (int i = 0; i < 4; ++i) { acc[i][0] = zero; acc[i][1] = zero; }

    float4 R0[2][2][2], R1[2][2][2];    // [kk][j][part], 2-slab deep
    bf16x8 afA[4][2], afB[4][2];

    auto loadB = [&](float4 (&R)[2][2][2], int s) {
        #pragma unroll
        for (int kk = 0; kk < 2; ++kk) {
            const int o = s * 64 + kk * 32;
            R[kk][0][0] = *(const float4*)(bp0 + o);
            R[kk][0][1] = *(const float4*)(bp0 + o + 4);
            R[kk][1][0] = *(const float4*)(bp1 + o);
            R[kk][1][1] = *(const float4*)(bp1 + o + 4);
        }
    };
    auto loadA = [&](bf16x8 (&af)[4][2], int s) {
        #pragma unroll
        for (int i = 0; i < 4; ++i)
            #pragma unroll
            for (int kk = 0; kk < 2; ++kk)
                af[i][kk] = *(const bf16x8*)(ap[i] + s * 64 + kk * 32);
    };
    auto compute = [&](const bf16x8 (&af)[4][2], const float4 (&R)[2][2][2]) {
        #pragma unroll
        for (int kk = 0; kk < 2; ++kk) {
            bf16x8 b0 = cvt8(R[kk][0][0], R[kk][0][1]);
            bf16x8 b1 = cvt8(R[kk][1][0], R[kk][1][1]);
            #pragma unroll
            for (int i = 0; i < 4; ++i) {
                acc[i][0] = __builtin_amdgcn_mfma_f32_16x16x32_bf16(af[i][kk], b0, acc[i][0], 0, 0, 0);
                acc[i][1] = __builtin_amdgcn_mfma_f32_16x16x32_bf16(af[i][kk], b1, acc[i][1], 0, 0, 0);
            }
        }
    };

    const int NK = IDIM / 64;   // 16
    loadB(R0, 0);
    loadA(afA, 0);
    loadB(R1, 1);
    for (int s = 0; s < NK; s += 2) {
        loadA(afB, s + 1);
        compute(afA, R0);
        if (s + 2 < NK) { loadB(R0, s + 2); loadA(afA, s + 2); }
        compute(afB, R1);
        if (s + 3 < NK) loadB(R1, s + 3);
    }

    #pragma unroll
    for (int i = 0; i < 4; ++i) {
        #pragma unroll
        for (int r = 0; r < 4; ++r) {
            int mrow = m0 + i * 16 + quad * 4 + r;
            if (mrow < cnt) {
                int p = pairs[seg + mrow];               // == t*K+k = out row
                size_t ob = (size_t)p * HDIM + n0 + l16;
                out[ob]      = acc[i][0][r];
                out[ob + 16] = acc[i][1][r];
            }
        }
    }
}

// ---------------------------------------------------------------------------
extern "C" void kernel_launch(void* const* d_in, const int* in_sizes, int n_in,
                              void* d_out, int out_size, void* d_ws, size_t ws_size,
                              hipStream_t stream) {
    const float* hidden = (const float*)d_in[0];   // (T, H) fp32
    const int*   sel    = (const int*)  d_in[1];   // (T, K) int32
    const float* gup    = (const float*)d_in[2];   // (E, 2I, H) fp32
    const float* down   = (const float*)d_in[3];   // (E, H, I) fp32
    float* out = (float*)d_out;                    // (T, K, H) fp32

    // ws: meta 16 ints | pairs 2048 ints | inter bf16 2048x1024 (4 MB)
    //     | hid_bf bf16 1024x2048 (4 MB)   -- total ~8.1 MB
    char* ws = (char*)d_ws;
    int* meta  = (int*)ws;
    int* pairs = meta + 16;
    unsigned short* inter  = (unsigned short*)(ws + 16384);
    unsigned short* hid_bf = inter + (size_t)TK * IDIM;

    prep<<<T_TOK * HDIM / 8 / 256, 256, 0, stream>>>(hidden, sel, hid_bf, meta, pairs);
    // 8 experts x 96 block-groups x 4 waves = 384 waves/expert = 64 nt x 6 mi
    gemm1_gateup<<<8 * 96, 256, 0, stream>>>(hid_bf, gup, meta, pairs, inter);
    gemm2_down  <<<8 * 96, 256, 0, stream>>>(inter, down, meta, pairs, out);
}

// Round 9
// 289.825 us; speedup vs baseline: 1.5827x; 1.5827x over previous
//
#include <hip/hip_runtime.h>
#include <hip/hip_bf16.h>

// Problem constants (T,K,E,H,I) = (1024, 2, 8, 2048, 1024)
#define T_TOK 1024
#define KSEL  2
#define NEXP  8
#define HDIM  2048
#define IDIM  1024
#define TK    2048            // (token, slot) pairs

#define BR 72                 // LDS row stride in bf16 elems (64 payload + 8 pad = 144 B)

typedef float  f32x4  __attribute__((ext_vector_type(4)));
typedef __bf16 bf16x8 __attribute__((ext_vector_type(8)));
typedef __bf16 bf16x2 __attribute__((ext_vector_type(2)));

__device__ __forceinline__ unsigned short f2bf(float f) {
    union { float f; unsigned u; } v; v.f = f;
    unsigned r = (v.u >> 16) & 1u;               // round-to-nearest-even
    return (unsigned short)((v.u + 0x7fffu + r) >> 16);
}

__device__ __forceinline__ unsigned pk2bf(float lo, float hi) {
#if __has_builtin(__builtin_amdgcn_cvt_pk_bf16_f32)
    bf16x2 v = __builtin_amdgcn_cvt_pk_bf16_f32(lo, hi);
    union { bf16x2 v; unsigned u; } c; c.v = v;
    return c.u;
#else
    return (unsigned)f2bf(lo) | ((unsigned)f2bf(hi) << 16);
#endif
}

// ---------------------------------------------------------------------------
// Kernel 1: prep = hidden fp32->bf16 (all blocks) + expert counting-sort
// (block 0 only). Grid 1024 x 256 covers T*H/8 = 262144 chunks exactly.
// ---------------------------------------------------------------------------
__global__ __launch_bounds__(256) void prep(
    const float* __restrict__ hidden, const int* __restrict__ sel,
    unsigned short* __restrict__ hid_bf, int* __restrict__ meta,
    int* __restrict__ pairs)
{
    const int t = blockIdx.x * 256 + threadIdx.x;
    {
        const float* s = hidden + (size_t)t * 8;
        float4 v0 = *(const float4*)s;
        float4 v1 = *(const float4*)(s + 4);
        uint4 o;
        o.x = pk2bf(v0.x, v0.y); o.y = pk2bf(v0.z, v0.w);
        o.z = pk2bf(v1.x, v1.y); o.w = pk2bf(v1.z, v1.w);
        *(uint4*)(hid_bf + (size_t)t * 8) = o;
    }
    if (blockIdx.x == 0) {
        __shared__ int lcnt[NEXP], lstart[NEXP], lfill[NEXP];
        const int tid = threadIdx.x;
        if (tid < NEXP) { lcnt[tid] = 0; lfill[tid] = 0; }
        __syncthreads();
        for (int i = tid; i < TK; i += 256) atomicAdd(&lcnt[sel[i]], 1);
        __syncthreads();
        if (tid == 0) {
            int s2 = 0;
            for (int e2 = 0; e2 < NEXP; ++e2) { lstart[e2] = s2; s2 += lcnt[e2]; }
        }
        __syncthreads();
        for (int i = tid; i < TK; i += 256) {
            int e2 = sel[i];
            pairs[lstart[e2] + atomicAdd(&lfill[e2], 1)] = i;   // i == t*K+k
        }
        if (tid < NEXP) { meta[tid] = lcnt[tid]; meta[NEXP + tid] = lstart[tid]; }
    }
}

// ---------------------------------------------------------------------------
// Kernel 2: gate_up GEMM + SiLU*up -> bf16 inter (packed rows).
// Block = 256 thr = 4 waves; wave w owns M rows [48w,48w+48) -> 192 rows.
// N = 32 inter cols (64 weight rows: 32 gate + 32 up).
// B staging lane-map (the r9 fix): flat id = tid + 256c, row = id>>4,
// chunk16B = id&15 -> 16 consecutive lanes read one row's 16 consecutive
// 16B chunks => fully-used 64B lines, minimal TA transactions.
// LDS triple-buffered, ONE barrier per slab; loads issue right after the
// previous barrier so compute covers latency before the vmcnt(0) drain.
// A fragments direct from hid_bf (16 full lines/instr; XCD-local L2,
// e = bx&7 pins expert->XCD). K-slab 64, NK=32.
// Grid mt(2) x nt(32) x e(8) = 512 blocks = 2/CU.
// ---------------------------------------------------------------------------
__global__ __launch_bounds__(256, 2) void gemm1_gateup(
    const unsigned short* __restrict__ hid_bf, const float* __restrict__ gup,
    const int* __restrict__ meta, const int* __restrict__ pairs,
    unsigned short* __restrict__ inter)
{
    __shared__ __align__(16) unsigned short Bs[3][64 * BR];

    const int bx = blockIdx.x;
    const int e = bx & 7, nt = (bx >> 3) & 31, mt = bx >> 8;
    const int cnt = meta[e];
    const int m0 = mt * 192;
    if (m0 >= cnt) return;                    // block-uniform exit
    const int seg  = meta[8 + e];
    const int rows = cnt - m0;
    const int n0   = nt * 32;

    const int tid  = threadIdx.x;
    const int lane = tid & 63, w = tid >> 6;  // w in [0,4)
    const int quad = lane >> 4, l16 = lane & 15;

    // B staging: 64 rows x 16 chunks = 1024 chunk-slots; 4 per thread.
    const float* bp[4]; int bofs[4];
    #pragma unroll
    for (int c = 0; c < 4; ++c) {
        int id = tid + c * 256;
        int brow = id >> 4, kc = id & 15;
        int grow = (brow < 32) ? (n0 + brow) : (IDIM + n0 + (brow - 32));
        bp[c]   = gup + (size_t)e * (2 * IDIM * HDIM) + (size_t)grow * HDIM + kc * 4;
        bofs[c] = brow * BR + kc * 4;
    }

    // A fragment base pointers: 3 m-frags of 16 rows; lane row = l16.
    const unsigned short* ap[3];
    #pragma unroll
    for (int i = 0; i < 3; ++i) {
        int mr  = m0 + w * 48 + i * 16 + l16;
        int idx = seg + min(mr, cnt - 1);     // clamp; dup rows masked at store
        ap[i] = hid_bf + (size_t)(pairs[idx] >> 1) * HDIM + quad * 8;
    }

    f32x4 accg[3][2], accu[3][2];
    const f32x4 zero = {0.f, 0.f, 0.f, 0.f};
    #pragma unroll
    for (int i = 0; i < 3; ++i)
        #pragma unroll
        for (int j = 0; j < 2; ++j) { accg[i][j] = zero; accu[i][j] = zero; }

    float4 X[4], Y[4];                        // raw B, two slab-sets
    bf16x8 afC[3][2], afN[3][2];              // A frags, current/next slab

    auto loadB = [&](float4 (&R)[4], int s) {
        #pragma unroll
        for (int c = 0; c < 4; ++c) R[c] = *(const float4*)(bp[c] + s * 64);
    };
    auto storeB = [&](const float4 (&R)[4], int buf) {
        #pragma unroll
        for (int c = 0; c < 4; ++c) {
            ushort4 o;
            o.x = (unsigned short)(pk2bf(R[c].x, R[c].y) & 0xffff);
            o.y = (unsigned short)(pk2bf(R[c].x, R[c].y) >> 16);
            o.z = (unsigned short)(pk2bf(R[c].z, R[c].w) & 0xffff);
            o.w = (unsigned short)(pk2bf(R[c].z, R[c].w) >> 16);
            *(ushort4*)&Bs[buf][bofs[c]] = o;
        }
    };
    auto loadA = [&](bf16x8 (&af)[3][2], int s) {
        #pragma unroll
        for (int i = 0; i < 3; ++i)
            #pragma unroll
            for (int kk = 0; kk < 2; ++kk)
                af[i][kk] = *(const bf16x8*)(ap[i] + s * 64 + kk * 32);
    };
    auto compute = [&](const bf16x8 (&af)[3][2], int buf) {
        #pragma unroll
        for (int kk = 0; kk < 2; ++kk) {
            const int ko = kk * 32 + quad * 8;
            bf16x8 bg[2], bu[2];
            #pragma unroll
            for (int j = 0; j < 2; ++j) {
                bg[j] = *(const bf16x8*)&Bs[buf][(j * 16 + l16) * BR + ko];
                bu[j] = *(const bf16x8*)&Bs[buf][(32 + j * 16 + l16) * BR + ko];
            }
            #pragma unroll
            for (int i = 0; i < 3; ++i)
                #pragma unroll
                for (int j = 0; j < 2; ++j) {
                    accg[i][j] = __builtin_amdgcn_mfma_f32_16x16x32_bf16(af[i][kk], bg[j], accg[i][j], 0, 0, 0);
                    accu[i][j] = __builtin_amdgcn_mfma_f32_16x16x32_bf16(af[i][kk], bu[j], accu[i][j], 0, 0, 0);
                }
        }
    };

    const int NK = HDIM / 64;   // 32
    loadB(X, 0);
    loadB(Y, 1);
    loadA(afC, 0);
    storeB(X, 0);
    __syncthreads();            // buf0 ready

    for (int s = 0; s < NK; s += 2) {
        // --- slab s: read buf s%3, fill buf (s+1)%3 from Y ---
        if (s + 2 < NK) loadB(X, s + 2);
        loadA(afN, s + 1);
        storeB(Y, (s + 1) % 3);
        compute(afC, s % 3);
        __syncthreads();
        // --- slab s+1: read buf (s+1)%3, fill buf (s+2)%3 from X ---
        if (s + 3 < NK) loadB(Y, s + 3);
        if (s + 2 < NK) { loadA(afC, s + 2); storeB(X, (s + 2) % 3); }
        compute(afN, (s + 1) % 3);
        __syncthreads();
    }

    // Epilogue: silu(gate)*up -> inter (packed rows, bf16).
    #pragma unroll
    for (int i = 0; i < 3; ++i) {
        #pragma unroll
        for (int r = 0; r < 4; ++r) {
            int mrow = w * 48 + i * 16 + quad * 4 + r;
            if (mrow < rows && mrow < 192) {
                size_t orow = (size_t)(seg + m0 + mrow) * IDIM;
                #pragma unroll
                for (int j = 0; j < 2; ++j) {
                    float g = accg[i][j][r], u = accu[i][j][r];
                    float sv = g * (1.f / (1.f + __expf(-g)));
                    inter[orow + n0 + j * 16 + l16] = f2bf(sv * u);
                }
            }
        }
    }
}

// ---------------------------------------------------------------------------
// Kernel 3: down-proj GEMM. Same skeleton: M192 x N64, B = 64 down rows fp32
// (optimal staging lane-map), A = inter bf16 direct from L2. K-slab 64,
// NK=16, triple buffer, one barrier/slab. Grid mt(2) x nt(32) x e(8) = 512.
// Output fp32 scattered to out[pairs[p]].
// ---------------------------------------------------------------------------
__global__ __launch_bounds__(256, 2) void gemm2_down(
    const unsigned short* __restrict__ inter, const float* __restrict__ down,
    const int* __restrict__ meta, const int* __restrict__ pairs,
    float* __restrict__ out)
{
    __shared__ __align__(16) unsigned short Bs[3][64 * BR];

    const int bx = blockIdx.x;
    const int e = bx & 7, nt = (bx >> 3) & 31, mt = bx >> 8;
    const int cnt = meta[e];
    const int m0 = mt * 192;
    if (m0 >= cnt) return;
    const int seg  = meta[8 + e];
    const int rows = cnt - m0;
    const int n0   = nt * 64;

    const int tid  = threadIdx.x;
    const int lane = tid & 63, w = tid >> 6;
    const int quad = lane >> 4, l16 = lane & 15;

    const float* bp[4]; int bofs[4];
    #pragma unroll
    for (int c = 0; c < 4; ++c) {
        int id = tid + c * 256;
        int brow = id >> 4, kc = id & 15;
        bp[c]   = down + (size_t)e * (HDIM * IDIM) + (size_t)(n0 + brow) * IDIM + kc * 4;
        bofs[c] = brow * BR + kc * 4;
    }

    const unsigned short* ap[3];
    #pragma unroll
    for (int i = 0; i < 3; ++i) {
        int mr  = m0 + w * 48 + i * 16 + l16;
        int idx = seg + min(mr, cnt - 1);
        ap[i] = inter + (size_t)idx * IDIM + quad * 8;
    }

    f32x4 acc[3][4];
    const f32x4 zero = {0.f, 0.f, 0.f, 0.f};
    #pragma unroll
    for (int i = 0; i < 3; ++i)
        #pragma unroll
        for (int j = 0; j < 4; ++j) acc[i][j] = zero;

    float4 X[4], Y[4];
    bf16x8 afC[3][2], afN[3][2];

    auto loadB = [&](float4 (&R)[4], int s) {
        #pragma unroll
        for (int c = 0; c < 4; ++c) R[c] = *(const float4*)(bp[c] + s * 64);
    };
    auto storeB = [&](const float4 (&R)[4], int buf) {
        #pragma unroll
        for (int c = 0; c < 4; ++c) {
            ushort4 o;
            o.x = (unsigned short)(pk2bf(R[c].x, R[c].y) & 0xffff);
            o.y = (unsigned short)(pk2bf(R[c].x, R[c].y) >> 16);
            o.z = (unsigned short)(pk2bf(R[c].z, R[c].w) & 0xffff);
            o.w = (unsigned short)(pk2bf(R[c].z, R[c].w) >> 16);
            *(ushort4*)&Bs[buf][bofs[c]] = o;
        }
    };
    auto loadA = [&](bf16x8 (&af)[3][2], int s) {
        #pragma unroll
        for (int i = 0; i < 3; ++i)
            #pragma unroll
            for (int kk = 0; kk < 2; ++kk)
                af[i][kk] = *(const bf16x8*)(ap[i] + s * 64 + kk * 32);
    };
    auto compute = [&](const bf16x8 (&af)[3][2], int buf) {
        #pragma unroll
        for (int kk = 0; kk < 2; ++kk) {
            const int ko = kk * 32 + quad * 8;
            bf16x8 bf[4];
            #pragma unroll
            for (int j = 0; j < 4; ++j)
                bf[j] = *(const bf16x8*)&Bs[buf][(j * 16 + l16) * BR + ko];
            #pragma unroll
            for (int i = 0; i < 3; ++i)
                #pragma unroll
                for (int j = 0; j < 4; ++j)
                    acc[i][j] = __builtin_amdgcn_mfma_f32_16x16x32_bf16(af[i][kk], bf[j], acc[i][j], 0, 0, 0);
        }
    };

    const int NK = IDIM / 64;   // 16
    loadB(X, 0);
    loadB(Y, 1);
    loadA(afC, 0);
    storeB(X, 0);
    __syncthreads();

    for (int s = 0; s < NK; s += 2) {
        if (s + 2 < NK) loadB(X, s + 2);
        loadA(afN, s + 1);
        storeB(Y, (s + 1) % 3);
        compute(afC, s % 3);
        __syncthreads();
        if (s + 3 < NK) loadB(Y, s + 3);
        if (s + 2 < NK) { loadA(afC, s + 2); storeB(X, (s + 2) % 3); }
        compute(afN, (s + 1) % 3);
        __syncthreads();
    }

    #pragma unroll
    for (int i = 0; i < 3; ++i) {
        #pragma unroll
        for (int r = 0; r < 4; ++r) {
            int mrow = w * 48 + i * 16 + quad * 4 + r;
            if (mrow < rows && mrow < 192) {
                int p = pairs[seg + m0 + mrow];          // == t*K+k = out row
                size_t ob = (size_t)p * HDIM + n0 + l16;
                #pragma unroll
                for (int j = 0; j < 4; ++j)
                    out[ob + j * 16] = acc[i][j][r];
            }
        }
    }
}

// ---------------------------------------------------------------------------
extern "C" void kernel_launch(void* const* d_in, const int* in_sizes, int n_in,
                              void* d_out, int out_size, void* d_ws, size_t ws_size,
                              hipStream_t stream) {
    const float* hidden = (const float*)d_in[0];   // (T, H) fp32
    const int*   sel    = (const int*)  d_in[1];   // (T, K) int32
    const float* gup    = (const float*)d_in[2];   // (E, 2I, H) fp32
    const float* down   = (const float*)d_in[3];   // (E, H, I) fp32
    float* out = (float*)d_out;                    // (T, K, H) fp32

    // ws: meta 16 ints | pairs 2048 ints | inter bf16 2048x1024 (4 MB)
    //     | hid_bf bf16 1024x2048 (4 MB)   -- total ~8.1 MB
    char* ws = (char*)d_ws;
    int* meta  = (int*)ws;
    int* pairs = meta + 16;
    unsigned short* inter  = (unsigned short*)(ws + 16384);
    unsigned short* hid_bf = inter + (size_t)TK * IDIM;

    prep<<<T_TOK * HDIM / 8 / 256, 256, 0, stream>>>(hidden, sel, hid_bf, meta, pairs);
    gemm1_gateup<<<2 * 32 * 8, 256, 0, stream>>>(hid_bf, gup, meta, pairs, inter);
    gemm2_down  <<<2 * 32 * 8, 256, 0, stream>>>(inter, down, meta, pairs, out);
}